// Round 7
// baseline (1064.342 us; speedup 1.0000x reference)
//
#include <hip/hip_runtime.h>

// ============================================================================
// 2-layer Elman RNN (tanh), SEQ=1024 B=256 F=64 H=128, fp32 in/out.
// R6: WAVE-SPECIALIZED layers. R3/R4 identical at 896us despite different
// exchange/barrier code -> bottleneck is per-wave issue serialization
// (1 wave/SIMD, both layers serial in program order, ~900 cyc issue + unhidden
// stalls). R6: 16 blocks x 512 thr (8 waves, 2/SIMD):
//   waves 0-3: layer 0 only (x*Wih0 + h0*Whh0), 32 hid cols each
//   waves 4-7: layer 1 only (h0*Wih1 + h1*Whh1), 32 hid cols each, y1 stores
// Layers run in PARALLEL on different SIMDs (1-step lag pipeline); per-wave
// issue ~halves; 2 waves/SIMD hide ds_read/MFMA/trans latency.
// Weights: group-specific contents loaded into shared WA/WB arrays under the
// wave-uniform branch (no register duplication across groups).
// Slot map (unchanged from R4): slot S = c_lsb*8 + c_hi for hid col c.
//   write: thread (wv,r16,g4) packs (n=0,1) -> half2 at row g4*4+i,
//          slot r16*8+wv*2. read: b128 row r16, slots q*32+g4*8: elem j <->
//          c = j*16+q*4+g4; h-paired weights gathered with SAME (q,g4,j)->k.
// ============================================================================

#define SEQ   1024
#define BATCH 256
#define FDIM  64
#define HID   128

typedef __attribute__((ext_vector_type(8))) _Float16 half8;
typedef __attribute__((ext_vector_type(2))) _Float16 half2v;
typedef __attribute__((ext_vector_type(4))) float    f32x4;

#define MFMA16(a, b, c) __builtin_amdgcn_mfma_f32_16x16x32_f16((a), (b), (c), 0, 0, 0)

__device__ __forceinline__ void lds_barrier() {
  // LDS-only fence + barrier (no vmcnt drain).
  asm volatile("s_waitcnt lgkmcnt(0)\n\ts_barrier" ::: "memory");
}

__device__ __forceinline__ float fast_tanh(float x) {
  float e = __builtin_amdgcn_exp2f(x * 2.8853900817779268f);
  return 1.0f - 2.0f * __builtin_amdgcn_rcpf(e + 1.0f);
}

__device__ __forceinline__ half8 cvt8(float4 a, float4 b) {
  half8 h;
  h[0] = (_Float16)a.x; h[1] = (_Float16)a.y; h[2] = (_Float16)a.z; h[3] = (_Float16)a.w;
  h[4] = (_Float16)b.x; h[5] = (_Float16)b.y; h[6] = (_Float16)b.z; h[7] = (_Float16)b.w;
  return h;
}

__device__ __forceinline__ half8 h8zero() {
  half8 v;
#pragma unroll
  for (int j = 0; j < 8; ++j) v[j] = (_Float16)0.0f;
  return v;
}

// Contiguous-k fragment (Wih0, pairs with x): lane holds W[row][k0..k0+7].
__device__ __forceinline__ half8 load_w_frag(const float* __restrict__ W,
                                             int row, int k0, int ld) {
  const float4* p = (const float4*)(W + row * ld + k0);
  float4 a = p[0], b = p[1];
  return cvt8(a, b);
}

// Permuted-k fragment (h-paired weights): elem j <-> k = j*16 + q*4 + g4.
__device__ __forceinline__ half8 load_w_perm(const float* __restrict__ W,
                                             int row, int q, int g4, int ld) {
  const float* p = W + row * ld + q * 4 + g4;
  half8 h;
#pragma unroll
  for (int j = 0; j < 8; ++j) h[j] = (_Float16)p[j * 16];
  return h;
}

__global__ __launch_bounds__(512, 2) void rnn_fused(
    const float* __restrict__ x,
    const float* __restrict__ Wih0, const float* __restrict__ bih0,
    const float* __restrict__ Whh0, const float* __restrict__ bhh0,
    const float* __restrict__ Wih1, const float* __restrict__ bih1,
    const float* __restrict__ Whh1, const float* __restrict__ bhh1,
    float* __restrict__ out)
{
  // [parity][layer][row 16][slot 136(pad)] fp16
  __shared__ alignas(16) _Float16 hp[2][2][16][136];
  const int tid  = threadIdx.x;
  const int wgrp = tid >> 8;        // 0 = layer-0 group, 1 = layer-1 group
  const int wv   = (tid >> 6) & 3;  // wave within group: hid cols [32wv,32wv+32)
  const int lane = tid & 63;
  const int r16  = lane & 15;
  const int g4   = lane >> 4;
  const int b0   = blockIdx.x << 4;
  const bool isL0 = (wgrp == 0);

  // ---------------- weights: group-specific contents, shared registers ------
  // L0: WB[n][0..1] = Bih0 (contiguous k, pairs with xA); WA = Bhh0 (perm k)
  // L1: WB = Bih1 (perm k, pairs with h0A);               WA = Bhh1 (perm k)
  half8 WA[2][4], WB[2][4];
  float bs[2];
#pragma unroll
  for (int n = 0; n < 2; ++n) {
    const int row = (wv << 5) + (n << 4) + r16;
    if (isL0) {
      WB[n][0] = load_w_frag(Wih0, row, 0 + (g4 << 3), FDIM);
      WB[n][1] = load_w_frag(Wih0, row, 32 + (g4 << 3), FDIM);
      WB[n][2] = h8zero();
      WB[n][3] = h8zero();
#pragma unroll
      for (int q = 0; q < 4; ++q) WA[n][q] = load_w_perm(Whh0, row, q, g4, HID);
      bs[n] = bih0[row] + bhh0[row];
    } else {
#pragma unroll
      for (int q = 0; q < 4; ++q) {
        WB[n][q] = load_w_perm(Wih1, row, q, g4, HID);
        WA[n][q] = load_w_perm(Whh1, row, q, g4, HID);
      }
      bs[n] = bih1[row] + bhh1[row];
    }
  }

  // ---------------- state ----------------
  half8 h0A[4], h1A[4];
#pragma unroll
  for (int q = 0; q < 4; ++q) { h0A[q] = h8zero(); h1A[q] = h8zero(); }

  // x prefetch (L0 group only)
  const float* xrow = x + (b0 + r16) * FDIM + (g4 << 3);
  const float* xnext = xrow + BATCH * FDIM;
  float4 xp[4];
  if (isL0) {
    xp[0] = *(const float4*)(xrow);
    xp[1] = *(const float4*)(xrow + 4);
    xp[2] = *(const float4*)(xrow + 32);
    xp[3] = *(const float4*)(xrow + 36);
  }

  // LDS: write row g4*4+i, slot r16*8+wv*2, own layer plane.
  _Float16* wb = &hp[0][wgrp][g4 << 2][(r16 << 3) + (wv << 1)];
  const _Float16* rb = &hp[0][0][r16][g4 << 3];

  float* ybase = out + (size_t)(b0 + (g4 << 2)) * HID + (wv << 5) + r16;

  float hf[2][4]; // L0: h0(t);  L1: h1(t-1)

#pragma unroll 2
  for (int t = 0; t < SEQ; ++t) {
    _Float16* w = wb + (t & 1) * 4352;

    if (isL0) {
      // ---- layer 0: h0(t) = tanh(bs + x(t)Wih0^T + h0(t-1)Whh0^T) ----
      half8 xA0 = cvt8(xp[0], xp[1]);
      half8 xA1 = cvt8(xp[2], xp[3]);
      if (t < SEQ - 1) {
        xp[0] = *(const float4*)(xnext);
        xp[1] = *(const float4*)(xnext + 4);
        xp[2] = *(const float4*)(xnext + 32);
        xp[3] = *(const float4*)(xnext + 36);
        xnext += BATCH * FDIM;
      }
#pragma unroll
      for (int n = 0; n < 2; ++n) {
        f32x4 a0 = {bs[n], bs[n], bs[n], bs[n]};
        f32x4 a1 = {0.f, 0.f, 0.f, 0.f};
        a0 = MFMA16(xA0, WB[n][0], a0);
        a1 = MFMA16(xA1, WB[n][1], a1);
        a0 = MFMA16(h0A[0], WA[n][0], a0);
        a1 = MFMA16(h0A[1], WA[n][1], a1);
        a0 = MFMA16(h0A[2], WA[n][2], a0);
        a1 = MFMA16(h0A[3], WA[n][3], a1);
#pragma unroll
        for (int i = 0; i < 4; ++i) hf[n][i] = fast_tanh(a0[i] + a1[i]);
      }
#pragma unroll
      for (int i = 0; i < 4; ++i) {
        half2v v; v[0] = (_Float16)hf[0][i]; v[1] = (_Float16)hf[1][i];
        *(half2v*)(w + i * 136) = v;
      }
    } else {
      // ---- layer 1: h1(t-1) = tanh(bs + h0(t-1)Wih1^T + h1(t-2)Whh1^T) ----
#pragma unroll
      for (int n = 0; n < 2; ++n) {
        f32x4 a0 = {bs[n], bs[n], bs[n], bs[n]};
        f32x4 a1 = {0.f, 0.f, 0.f, 0.f};
        a0 = MFMA16(h0A[0], WB[n][0], a0);
        a1 = MFMA16(h0A[1], WB[n][1], a1);
        a0 = MFMA16(h0A[2], WB[n][2], a0);
        a1 = MFMA16(h0A[3], WB[n][3], a1);
        a0 = MFMA16(h1A[0], WA[n][0], a0);
        a1 = MFMA16(h1A[1], WA[n][1], a1);
        a0 = MFMA16(h1A[2], WA[n][2], a0);
        a1 = MFMA16(h1A[3], WA[n][3], a1);
#pragma unroll
        for (int i = 0; i < 4; ++i) hf[n][i] = fast_tanh(a0[i] + a1[i]);
      }
      if (t > 0) { // y1[t-1] (h1(-1) at t==0 is garbage, never stored)
        float* yo = ybase + (size_t)(t - 1) * (BATCH * HID);
#pragma unroll
        for (int n = 0; n < 2; ++n)
#pragma unroll
          for (int i = 0; i < 4; ++i) yo[i * HID + n * 16] = hf[n][i];
      }
#pragma unroll
      for (int i = 0; i < 4; ++i) {
        half2v v; v[0] = (_Float16)hf[0][i]; v[1] = (_Float16)hf[1][i];
        *(half2v*)(w + i * 136) = v;
      }
    }

    lds_barrier();
    {
      const _Float16* r = rb + (t & 1) * 4352;
#pragma unroll
      for (int q = 0; q < 4; ++q) h0A[q] = *(const half8*)(r + q * 32);
      if (!isL0) {
#pragma unroll
        for (int q = 0; q < 4; ++q) h1A[q] = *(const half8*)(r + 2176 + q * 32);
        if (t == 0) { // h1(-1) must be 0, not the garbage just exchanged
#pragma unroll
          for (int q = 0; q < 4; ++q) h1A[q] = h8zero();
        }
      }
    }
  }

  // ---- epilogue ----
  if (isL0) {
    // hf = h0(1023) -> h_n layer 0
    float* hn0 = out + (size_t)SEQ * BATCH * HID +
                 (size_t)(b0 + (g4 << 2)) * HID + (wv << 5) + r16;
#pragma unroll
    for (int n = 0; n < 2; ++n)
#pragma unroll
      for (int i = 0; i < 4; ++i) hn0[i * HID + n * 16] = hf[n][i];
  } else {
    // h1(1023) = tanh(bs + h0(1023)Wih1^T + h1(1022)Whh1^T); regs are current.
    float h1l[2][4];
#pragma unroll
    for (int n = 0; n < 2; ++n) {
      f32x4 a0 = {bs[n], bs[n], bs[n], bs[n]};
      f32x4 a1 = {0.f, 0.f, 0.f, 0.f};
      a0 = MFMA16(h0A[0], WB[n][0], a0);
      a1 = MFMA16(h0A[1], WB[n][1], a1);
      a0 = MFMA16(h0A[2], WB[n][2], a0);
      a1 = MFMA16(h0A[3], WB[n][3], a1);
      a0 = MFMA16(h1A[0], WA[n][0], a0);
      a1 = MFMA16(h1A[1], WA[n][1], a1);
      a0 = MFMA16(h1A[2], WA[n][2], a0);
      a1 = MFMA16(h1A[3], WA[n][3], a1);
#pragma unroll
      for (int i = 0; i < 4; ++i) h1l[n][i] = fast_tanh(a0[i] + a1[i]);
    }
    float* yo = ybase + (size_t)(SEQ - 1) * (BATCH * HID);
    float* hn1 = out + (size_t)SEQ * BATCH * HID + (size_t)BATCH * HID +
                 (size_t)(b0 + (g4 << 2)) * HID + (wv << 5) + r16;
#pragma unroll
    for (int n = 0; n < 2; ++n)
#pragma unroll
      for (int i = 0; i < 4; ++i) {
        yo[i * HID + n * 16]  = h1l[n][i];
        hn1[i * HID + n * 16] = h1l[n][i];
      }
  }
}

extern "C" void kernel_launch(void* const* d_in, const int* in_sizes, int n_in,
                              void* d_out, int out_size, void* d_ws, size_t ws_size,
                              hipStream_t stream) {
  (void)in_sizes; (void)n_in; (void)out_size; (void)d_ws; (void)ws_size;
  const float* x    = (const float*)d_in[0];
  const float* Wih0 = (const float*)d_in[1];
  const float* bih0 = (const float*)d_in[2];
  const float* Whh0 = (const float*)d_in[3];
  const float* bhh0 = (const float*)d_in[4];
  const float* Wih1 = (const float*)d_in[5];
  const float* bih1 = (const float*)d_in[6];
  const float* Whh1 = (const float*)d_in[7];
  const float* bhh1 = (const float*)d_in[8];
  rnn_fused<<<16, 512, 0, stream>>>(x, Wih0, bih0, Whh0, bhh0,
                                    Wih1, bih1, Whh1, bhh1, (float*)d_out);
}

// Round 9
// 852.137 us; speedup vs baseline: 1.2490x; 1.2490x over previous
//
#include <hip/hip_runtime.h>
#include <type_traits>

// ============================================================================
// 2-layer Elman RNN (tanh), SEQ=1024 B=256 F=64 H=128, fp32 in/out.
// R8: R3/R4/R6 all ~900us despite different compute structure -> step time is
// pinned by LOAD LATENCY (1-deep x prefetch), not issue count.
//   Kernel 1 (gemm_xw, 4096 blocks, all CUs): xw = x*Wih0^T + bih0 + bhh0,
//     stored fp32 in C-fragment-ready layout [mblk][n][g4][r16][i].
//   Kernel 2 (rnn_scan, 16 blocks x 512): L0 seeds acc from xw (4 MFMA chain,
//     depth 2), xw prefetched 3 STEPS AHEAD via 4-slot static ring buffer.
//     L1 chain split into 4 accumulators (depth 2). Slot-map LDS exchange +
//     lgkm-only barrier unchanged from R6.
// ws_size runtime check: fp32 xw (128MB) if it fits, else fp16 (64MB).
// ============================================================================

#define SEQ   1024
#define BATCH 256
#define FDIM  64
#define HID   128

typedef __attribute__((ext_vector_type(8))) _Float16 half8;
typedef __attribute__((ext_vector_type(4))) _Float16 half4v;
typedef __attribute__((ext_vector_type(2))) _Float16 half2v;
typedef __attribute__((ext_vector_type(4))) float    f32x4;

#define MFMA16(a, b, c) __builtin_amdgcn_mfma_f32_16x16x32_f16((a), (b), (c), 0, 0, 0)

__device__ __forceinline__ void lds_barrier() {
  asm volatile("s_waitcnt lgkmcnt(0)\n\ts_barrier" ::: "memory");
}

__device__ __forceinline__ float fast_tanh(float x) {
  float e = __builtin_amdgcn_exp2f(x * 2.8853900817779268f);
  return 1.0f - 2.0f * __builtin_amdgcn_rcpf(e + 1.0f);
}

__device__ __forceinline__ half8 cvt8(float4 a, float4 b) {
  half8 h;
  h[0] = (_Float16)a.x; h[1] = (_Float16)a.y; h[2] = (_Float16)a.z; h[3] = (_Float16)a.w;
  h[4] = (_Float16)b.x; h[5] = (_Float16)b.y; h[6] = (_Float16)b.z; h[7] = (_Float16)b.w;
  return h;
}

__device__ __forceinline__ half8 h8zero() {
  half8 v;
#pragma unroll
  for (int j = 0; j < 8; ++j) v[j] = (_Float16)0.0f;
  return v;
}

// Contiguous-k fragment: lane holds W[row][k0..k0+7] fp16.
__device__ __forceinline__ half8 load_w_frag(const float* __restrict__ W,
                                             int row, int k0, int ld) {
  const float4* p = (const float4*)(W + row * ld + k0);
  float4 a = p[0], b = p[1];
  return cvt8(a, b);
}

// Permuted-k fragment (h-paired weights): elem j <-> k = j*16 + q*4 + g4.
__device__ __forceinline__ half8 load_w_perm(const float* __restrict__ W,
                                             int row, int q, int g4, int ld) {
  const float* p = W + row * ld + q * 4 + g4;
  half8 h;
#pragma unroll
  for (int j = 0; j < 8; ++j) h[j] = (_Float16)p[j * 16];
  return h;
}

__device__ __forceinline__ f32x4 seed_cvt(float4 v) {
  f32x4 r; r[0] = v.x; r[1] = v.y; r[2] = v.z; r[3] = v.w; return r;
}
__device__ __forceinline__ f32x4 seed_cvt(half4v v) {
  f32x4 r; r[0] = (float)v[0]; r[1] = (float)v[1]; r[2] = (float)v[2]; r[3] = (float)v[3];
  return r;
}

// ======================= kernel 1: xw precompute ===========================
// xw[(mblk*8+n)*64 + g4*16 + r16] (float4/half4 units) holds, over i=0..3,
// xw for batch-in-tile row g4*4+i, hid col n*16+r16, where mblk = (t*256+b)/16.
template<int XF32>
__global__ __launch_bounds__(256) void gemm_xw(
    const float* __restrict__ x, const float* __restrict__ Wih0,
    const float* __restrict__ bih0, const float* __restrict__ bhh0,
    void* __restrict__ xw)
{
  const int tid = threadIdx.x, w = tid >> 6, lane = tid & 63;
  const int r16 = lane & 15, g4 = lane >> 4;
  const size_t mbase = (size_t)blockIdx.x * 64 + w * 16;
  const size_t mblk  = (size_t)blockIdx.x * 4 + w;

  half8 Bw[8][2]; float bv[8];
#pragma unroll
  for (int n = 0; n < 8; ++n) {
    const int row = n * 16 + r16;
    Bw[n][0] = load_w_frag(Wih0, row, (g4 << 3), FDIM);
    Bw[n][1] = load_w_frag(Wih0, row, 32 + (g4 << 3), FDIM);
    bv[n] = bih0[row] + bhh0[row];
  }
  const float* xr = x + (mbase + r16) * FDIM + (g4 << 3);
  float4 x0 = *(const float4*)(xr),      x1 = *(const float4*)(xr + 4);
  float4 x2 = *(const float4*)(xr + 32), x3 = *(const float4*)(xr + 36);
  half8 A0 = cvt8(x0, x1), A1 = cvt8(x2, x3);

#pragma unroll
  for (int n = 0; n < 8; ++n) {
    f32x4 acc = {bv[n], bv[n], bv[n], bv[n]};
    acc = MFMA16(A0, Bw[n][0], acc);
    acc = MFMA16(A1, Bw[n][1], acc);
    const size_t idx = (mblk * 8 + n) * 64 + (g4 << 4) + r16;
    if constexpr (XF32) {
      float4 s; s.x = acc[0]; s.y = acc[1]; s.z = acc[2]; s.w = acc[3];
      ((float4*)xw)[idx] = s;
    } else {
      half4v s; s[0] = (_Float16)acc[0]; s[1] = (_Float16)acc[1];
      s[2] = (_Float16)acc[2]; s[3] = (_Float16)acc[3];
      ((half4v*)xw)[idx] = s;
    }
  }
}

// ======================= kernel 2: sequential scan =========================
template<int XF32>
__global__ __launch_bounds__(512, 1) void rnn_scan(
    const void* __restrict__ xwv,
    const float* __restrict__ Whh0,
    const float* __restrict__ Wih1, const float* __restrict__ bih1,
    const float* __restrict__ Whh1, const float* __restrict__ bhh1,
    float* __restrict__ out)
{
  using XT = typename std::conditional<XF32 != 0, float4, half4v>::type;
  __shared__ alignas(16) _Float16 hp[2][2][16][136];
  const int tid  = threadIdx.x;
  const int wgrp = tid >> 8;        // 0 = layer-0 waves, 1 = layer-1 waves
  const int wv   = (tid >> 6) & 3;  // hid cols [32wv, 32wv+32)
  const int lane = tid & 63;
  const int r16  = lane & 15;
  const int g4   = lane >> 4;
  const int blk  = blockIdx.x;
  const int b0   = blk << 4;
  const bool isL0 = (wgrp == 0);

  // L0: WA = Bhh0 (perm k). L1: WB = Bih1, WA = Bhh1 (perm k).
  half8 WA[2][4], WB[2][4];
  float bs[2];
#pragma unroll
  for (int n = 0; n < 2; ++n) {
    const int row = (wv << 5) + (n << 4) + r16;
    if (isL0) {
#pragma unroll
      for (int q = 0; q < 4; ++q) { WA[n][q] = load_w_perm(Whh0, row, q, g4, HID); WB[n][q] = h8zero(); }
      bs[n] = 0.f;
    } else {
#pragma unroll
      for (int q = 0; q < 4; ++q) {
        WB[n][q] = load_w_perm(Wih1, row, q, g4, HID);
        WA[n][q] = load_w_perm(Whh1, row, q, g4, HID);
      }
      bs[n] = bih1[row] + bhh1[row];
    }
  }

  half8 h0A[4], h1A[4];
#pragma unroll
  for (int q = 0; q < 4; ++q) { h0A[q] = h8zero(); h1A[q] = h8zero(); }

  // xw indices (XT units): per step t add 8192; n-tile base:
  const XT* xw = (const XT*)xwv;
  size_t xb0 = ((size_t)blk * 8 + (wv << 1)) * 64 + (g4 << 4) + r16;
  size_t xb1 = xb0 + 64;

  XT ring[4][2]; // 3-step-ahead prefetch ring, statically indexed only
  if (isL0) {
    ring[0][0] = xw[xb0];            ring[0][1] = xw[xb1];
    ring[1][0] = xw[xb0 + 8192];     ring[1][1] = xw[xb1 + 8192];
    ring[2][0] = xw[xb0 + 16384];    ring[2][1] = xw[xb1 + 16384];
  }

  _Float16* wb = &hp[0][wgrp][g4 << 2][(r16 << 3) + (wv << 1)];
  const _Float16* rb = &hp[0][0][r16][g4 << 3];
  float* ybase = out + (size_t)(b0 + (g4 << 2)) * HID + (wv << 5) + r16;

  float hf[2][4]; // L0: h0(t);  L1: h1(t-1)

#define RNN_BODY(k)                                                            \
  {                                                                            \
    const int t = t0 + (k);                                                    \
    _Float16* w = wb + (((k) & 1) * 4352);                                     \
    if (isL0) {                                                                \
      const int tp = (t + 3 < SEQ) ? (t + 3) : (SEQ - 1);                      \
      ring[((k) + 3) & 3][0] = xw[xb0 + (size_t)tp * 8192];                    \
      ring[((k) + 3) & 3][1] = xw[xb1 + (size_t)tp * 8192];                    \
      _Pragma("unroll")                                                        \
      for (int n = 0; n < 2; ++n) {                                            \
        f32x4 a0 = seed_cvt(ring[(k)][n]);                                     \
        f32x4 a1 = {0.f, 0.f, 0.f, 0.f};                                       \
        a0 = MFMA16(h0A[0], WA[n][0], a0);                                     \
        a1 = MFMA16(h0A[1], WA[n][1], a1);                                     \
        a0 = MFMA16(h0A[2], WA[n][2], a0);                                     \
        a1 = MFMA16(h0A[3], WA[n][3], a1);                                     \
        _Pragma("unroll")                                                      \
        for (int i = 0; i < 4; ++i) hf[n][i] = fast_tanh(a0[i] + a1[i]);       \
      }                                                                        \
      _Pragma("unroll")                                                        \
      for (int i = 0; i < 4; ++i) {                                            \
        half2v v; v[0] = (_Float16)hf[0][i]; v[1] = (_Float16)hf[1][i];        \
        *(half2v*)(w + i * 136) = v;                                           \
      }                                                                        \
    } else {                                                                   \
      _Pragma("unroll")                                                        \
      for (int n = 0; n < 2; ++n) {                                            \
        f32x4 a0 = {bs[n], bs[n], bs[n], bs[n]};                               \
        f32x4 a1 = {0.f, 0.f, 0.f, 0.f};                                       \
        f32x4 a2 = {0.f, 0.f, 0.f, 0.f};                                       \
        f32x4 a3 = {0.f, 0.f, 0.f, 0.f};                                       \
        a0 = MFMA16(h0A[0], WB[n][0], a0);                                     \
        a1 = MFMA16(h0A[1], WB[n][1], a1);                                     \
        a2 = MFMA16(h0A[2], WB[n][2], a2);                                     \
        a3 = MFMA16(h0A[3], WB[n][3], a3);                                     \
        a0 = MFMA16(h1A[0], WA[n][0], a0);                                     \
        a1 = MFMA16(h1A[1], WA[n][1], a1);                                     \
        a2 = MFMA16(h1A[2], WA[n][2], a2);                                     \
        a3 = MFMA16(h1A[3], WA[n][3], a3);                                     \
        _Pragma("unroll")                                                      \
        for (int i = 0; i < 4; ++i)                                            \
          hf[n][i] = fast_tanh((a0[i] + a1[i]) + (a2[i] + a3[i]));             \
      }                                                                        \
      if (t > 0) {                                                             \
        float* yo = ybase + (size_t)(t - 1) * (BATCH * HID);                   \
        _Pragma("unroll")                                                      \
        for (int n = 0; n < 2; ++n)                                            \
          _Pragma("unroll")                                                    \
          for (int i = 0; i < 4; ++i) yo[i * HID + n * 16] = hf[n][i];         \
      }                                                                        \
      _Pragma("unroll")                                                        \
      for (int i = 0; i < 4; ++i) {                                            \
        half2v v; v[0] = (_Float16)hf[0][i]; v[1] = (_Float16)hf[1][i];        \
        *(half2v*)(w + i * 136) = v;                                           \
      }                                                                        \
    }                                                                          \
    lds_barrier();                                                             \
    {                                                                          \
      const _Float16* r = rb + (((k) & 1) * 4352);                             \
      _Pragma("unroll")                                                        \
      for (int q = 0; q < 4; ++q) h0A[q] = *(const half8*)(r + q * 32);        \
      if (!isL0) {                                                             \
        _Pragma("unroll")                                                      \
        for (int q = 0; q < 4; ++q) h1A[q] = *(const half8*)(r + 2176 + q * 32);\
        if (t == 0) {                                                          \
          _Pragma("unroll")                                                    \
          for (int q = 0; q < 4; ++q) h1A[q] = h8zero();                       \
        }                                                                      \
      }                                                                        \
    }                                                                          \
  }

#pragma unroll 1
  for (int t0 = 0; t0 < SEQ; t0 += 4) {
    RNN_BODY(0)
    RNN_BODY(1)
    RNN_BODY(2)
    RNN_BODY(3)
  }
#undef RNN_BODY

  // ---- epilogue ----
  if (isL0) {
    float* hn0 = out + (size_t)SEQ * BATCH * HID +
                 (size_t)(b0 + (g4 << 2)) * HID + (wv << 5) + r16;
#pragma unroll
    for (int n = 0; n < 2; ++n)
#pragma unroll
      for (int i = 0; i < 4; ++i) hn0[i * HID + n * 16] = hf[n][i];
  } else {
    float h1l[2][4];
#pragma unroll
    for (int n = 0; n < 2; ++n) {
      f32x4 a0 = {bs[n], bs[n], bs[n], bs[n]};
      f32x4 a1 = {0.f, 0.f, 0.f, 0.f};
      f32x4 a2 = {0.f, 0.f, 0.f, 0.f};
      f32x4 a3 = {0.f, 0.f, 0.f, 0.f};
      a0 = MFMA16(h0A[0], WB[n][0], a0);
      a1 = MFMA16(h0A[1], WB[n][1], a1);
      a2 = MFMA16(h0A[2], WB[n][2], a2);
      a3 = MFMA16(h0A[3], WB[n][3], a3);
      a0 = MFMA16(h1A[0], WA[n][0], a0);
      a1 = MFMA16(h1A[1], WA[n][1], a1);
      a2 = MFMA16(h1A[2], WA[n][2], a2);
      a3 = MFMA16(h1A[3], WA[n][3], a3);
#pragma unroll
      for (int i = 0; i < 4; ++i)
        h1l[n][i] = fast_tanh((a0[i] + a1[i]) + (a2[i] + a3[i]));
    }
    float* yo = ybase + (size_t)(SEQ - 1) * (BATCH * HID);
    float* hn1 = out + (size_t)SEQ * BATCH * HID + (size_t)BATCH * HID +
                 (size_t)(b0 + (g4 << 2)) * HID + (wv << 5) + r16;
#pragma unroll
    for (int n = 0; n < 2; ++n)
#pragma unroll
      for (int i = 0; i < 4; ++i) {
        yo[i * HID + n * 16]  = h1l[n][i];
        hn1[i * HID + n * 16] = h1l[n][i];
      }
  }
}

extern "C" void kernel_launch(void* const* d_in, const int* in_sizes, int n_in,
                              void* d_out, int out_size, void* d_ws, size_t ws_size,
                              hipStream_t stream) {
  (void)in_sizes; (void)n_in; (void)out_size;
  const float* x    = (const float*)d_in[0];
  const float* Wih0 = (const float*)d_in[1];
  const float* bih0 = (const float*)d_in[2];
  const float* Whh0 = (const float*)d_in[3];
  const float* bhh0 = (const float*)d_in[4];
  const float* Wih1 = (const float*)d_in[5];
  const float* bih1 = (const float*)d_in[6];
  const float* Whh1 = (const float*)d_in[7];
  const float* bhh1 = (const float*)d_in[8];
  float* out = (float*)d_out;

  const size_t nelem = (size_t)SEQ * BATCH * HID;
  const int nblk_gemm = (SEQ * BATCH) / 64; // 4096

  if (ws_size >= nelem * 4) {
    gemm_xw<1><<<nblk_gemm, 256, 0, stream>>>(x, Wih0, bih0, bhh0, d_ws);
    rnn_scan<1><<<16, 512, 0, stream>>>(d_ws, Whh0, Wih1, bih1, Whh1, bhh1, out);
  } else {
    gemm_xw<0><<<nblk_gemm, 256, 0, stream>>>(x, Wih0, bih0, bhh0, d_ws);
    rnn_scan<0><<<16, 512, 0, stream>>>(d_ws, Whh0, Wih1, bih1, Whh1, bhh1, out);
  }
}

// Round 11
// 824.025 us; speedup vs baseline: 1.2916x; 1.0341x over previous
//
#include <hip/hip_runtime.h>
#include <type_traits>

// ============================================================================
// 2-layer Elman RNN (tanh), SEQ=1024 B=256 F=64 H=128, fp32 in/out.
// R10 vs R9 (852us total = gemm 219 + scan 633):
//  1. gemm_xw: 512 grid-stride blocks (was 4096 one-shot). Weight frags loaded
//     ONCE per wave -> weight traffic 512MB -> 64MB. 8 m-tiles per wave with
//     1-deep x prefetch.
//  2. rnn_scan: READ-LINEAR LDS layout. R9 map was 8-way read-conflicted
//     (384 conflict cyc/step/CU measured). New map: value (m,c) stored at
//     halfidx B(c)*128 + m*8 + o(c), B = 4wv+(r16>>2), o = 2(r16&3)+n.
//     Reader lane's b128 for q-chunk = base + q*512 + lane*8 (halves) ->
//     exactly the linear conflict-free pattern. Writes: 4x b32, 8-way (cheap).
//     Weight gather bijection updated to match: k(q,g4,j) = q*32+(j&1)*16+
//     g4*4+(j>>1)  (A/B maps identical -> MFMA result invariant).
// Everything else (wave-specialized layers, 3-deep xw ring, lgkm-only
// barrier, fp16/fp32 ws fallback) unchanged from R9.
// ============================================================================

#define SEQ   1024
#define BATCH 256
#define FDIM  64
#define HID   128

typedef __attribute__((ext_vector_type(8))) _Float16 half8;
typedef __attribute__((ext_vector_type(4))) _Float16 half4v;
typedef __attribute__((ext_vector_type(2))) _Float16 half2v;
typedef __attribute__((ext_vector_type(4))) float    f32x4;

#define MFMA16(a, b, c) __builtin_amdgcn_mfma_f32_16x16x32_f16((a), (b), (c), 0, 0, 0)

__device__ __forceinline__ void lds_barrier() {
  asm volatile("s_waitcnt lgkmcnt(0)\n\ts_barrier" ::: "memory");
}

__device__ __forceinline__ float fast_tanh(float x) {
  float e = __builtin_amdgcn_exp2f(x * 2.8853900817779268f);
  return 1.0f - 2.0f * __builtin_amdgcn_rcpf(e + 1.0f);
}

__device__ __forceinline__ half8 cvt8(float4 a, float4 b) {
  half8 h;
  h[0] = (_Float16)a.x; h[1] = (_Float16)a.y; h[2] = (_Float16)a.z; h[3] = (_Float16)a.w;
  h[4] = (_Float16)b.x; h[5] = (_Float16)b.y; h[6] = (_Float16)b.z; h[7] = (_Float16)b.w;
  return h;
}

__device__ __forceinline__ half8 h8zero() {
  half8 v;
#pragma unroll
  for (int j = 0; j < 8; ++j) v[j] = (_Float16)0.0f;
  return v;
}

// Contiguous-k fragment (gemm only): lane holds W[row][k0..k0+7] fp16.
__device__ __forceinline__ half8 load_w_frag(const float* __restrict__ W,
                                             int row, int k0, int ld) {
  const float4* p = (const float4*)(W + row * ld + k0);
  float4 a = p[0], b = p[1];
  return cvt8(a, b);
}

// Permuted-k fragment matching the read-linear LDS map:
//   elem j <-> k = q*32 + (j&1)*16 + g4*4 + (j>>1)
__device__ __forceinline__ half8 load_w_perm(const float* __restrict__ W,
                                             int row, int q, int g4, int ld) {
  const float* p = W + row * ld + q * 32 + g4 * 4;
  half8 h;
#pragma unroll
  for (int j = 0; j < 8; ++j) h[j] = (_Float16)p[(j & 1) * 16 + (j >> 1)];
  return h;
}

__device__ __forceinline__ f32x4 seed_cvt(float4 v) {
  f32x4 r; r[0] = v.x; r[1] = v.y; r[2] = v.z; r[3] = v.w; return r;
}
__device__ __forceinline__ f32x4 seed_cvt(half4v v) {
  f32x4 r; r[0] = (float)v[0]; r[1] = (float)v[1]; r[2] = (float)v[2]; r[3] = (float)v[3];
  return r;
}

// ======================= kernel 1: xw precompute ===========================
// xw[(mt*8+n)*64 + g4*16 + r16] (float4/half4 units), mt = t*16 + bstrip.
// 512 grid-stride blocks; weights loaded once; 8 m-tiles per wave.
template<int XF32>
__global__ __launch_bounds__(256) void gemm_xw(
    const float* __restrict__ x, const float* __restrict__ Wih0,
    const float* __restrict__ bih0, const float* __restrict__ bhh0,
    void* __restrict__ xw)
{
  const int tid = threadIdx.x, w = tid >> 6, lane = tid & 63;
  const int r16 = lane & 15, g4 = lane >> 4;

  half8 Bw[8][2]; float bv[8];
#pragma unroll
  for (int n = 0; n < 8; ++n) {
    const int row = n * 16 + r16;
    Bw[n][0] = load_w_frag(Wih0, row, (g4 << 3), FDIM);
    Bw[n][1] = load_w_frag(Wih0, row, 32 + (g4 << 3), FDIM);
    bv[n] = bih0[row] + bhh0[row];
  }

  int mt = blockIdx.x * 4 + w;                       // wave-slot in [0,2048)
  const float* xr = x + (size_t)(mt * 16 + r16) * FDIM + (g4 << 3);
  float4 xp0 = *(const float4*)(xr),      xp1 = *(const float4*)(xr + 4);
  float4 xp2 = *(const float4*)(xr + 32), xp3 = *(const float4*)(xr + 36);

#pragma unroll
  for (int rep = 0; rep < 8; ++rep) {
    float4 n0, n1, n2, n3;
    if (rep < 7) {
      const float* xn = xr + (size_t)2048 * 16 * FDIM;
      n0 = *(const float4*)(xn);      n1 = *(const float4*)(xn + 4);
      n2 = *(const float4*)(xn + 32); n3 = *(const float4*)(xn + 36);
      xr = xn;
    }
    half8 A0 = cvt8(xp0, xp1), A1 = cvt8(xp2, xp3);
#pragma unroll
    for (int n = 0; n < 8; ++n) {
      f32x4 acc = {bv[n], bv[n], bv[n], bv[n]};
      acc = MFMA16(A0, Bw[n][0], acc);
      acc = MFMA16(A1, Bw[n][1], acc);
      const size_t idx = ((size_t)mt * 8 + n) * 64 + (g4 << 4) + r16;
      if constexpr (XF32) {
        float4 s; s.x = acc[0]; s.y = acc[1]; s.z = acc[2]; s.w = acc[3];
        ((float4*)xw)[idx] = s;
      } else {
        half4v s; s[0] = (_Float16)acc[0]; s[1] = (_Float16)acc[1];
        s[2] = (_Float16)acc[2]; s[3] = (_Float16)acc[3];
        ((half4v*)xw)[idx] = s;
      }
    }
    mt += 2048;
    xp0 = n0; xp1 = n1; xp2 = n2; xp3 = n3;
  }
}

// ======================= kernel 2: sequential scan =========================
template<int XF32>
__global__ __launch_bounds__(512, 1) void rnn_scan(
    const void* __restrict__ xwv,
    const float* __restrict__ Whh0,
    const float* __restrict__ Wih1, const float* __restrict__ bih1,
    const float* __restrict__ Whh1, const float* __restrict__ bhh1,
    float* __restrict__ out)
{
  using XT = typename std::conditional<XF32 != 0, float4, half4v>::type;
  // flat planes: [parity][layer][2048 halves = 4KB]; read-linear layout.
  __shared__ alignas(16) _Float16 hp[2][2][2048];
  const int tid  = threadIdx.x;
  const int wgrp = tid >> 8;        // 0 = layer-0 waves, 1 = layer-1 waves
  const int wv   = (tid >> 6) & 3;  // hid cols [32wv, 32wv+32)
  const int lane = tid & 63;
  const int r16  = lane & 15;
  const int g4   = lane >> 4;
  const int blk  = blockIdx.x;
  const int b0   = blk << 4;
  const bool isL0 = (wgrp == 0);

  // L0: WA = Bhh0. L1: WB = Bih1, WA = Bhh1. (perm-k matching LDS map)
  half8 WA[2][4], WB[2][4];
  float bs[2];
#pragma unroll
  for (int n = 0; n < 2; ++n) {
    const int row = (wv << 5) + (n << 4) + r16;
    if (isL0) {
#pragma unroll
      for (int q = 0; q < 4; ++q) { WA[n][q] = load_w_perm(Whh0, row, q, g4, HID); WB[n][q] = h8zero(); }
      bs[n] = 0.f;
    } else {
#pragma unroll
      for (int q = 0; q < 4; ++q) {
        WB[n][q] = load_w_perm(Wih1, row, q, g4, HID);
        WA[n][q] = load_w_perm(Whh1, row, q, g4, HID);
      }
      bs[n] = bih1[row] + bhh1[row];
    }
  }

  half8 h0A[4], h1A[4];
#pragma unroll
  for (int q = 0; q < 4; ++q) { h0A[q] = h8zero(); h1A[q] = h8zero(); }

  const XT* xw = (const XT*)xwv;
  size_t xb0 = ((size_t)blk * 8 + (wv << 1)) * 64 + (g4 << 4) + r16;
  size_t xb1 = xb0 + 64;

  XT ring[4][2]; // 3-step-ahead prefetch ring, statically indexed only
  if (isL0) {
    ring[0][0] = xw[xb0];            ring[0][1] = xw[xb1];
    ring[1][0] = xw[xb0 + 8192];     ring[1][1] = xw[xb1 + 8192];
    ring[2][0] = xw[xb0 + 16384];    ring[2][1] = xw[xb1 + 16384];
  }

  // LDS pointers (half units), parity stride 4096.
  // write: B = 4wv + (r16>>2); halfidx = B*128 + g4*32 + (r16&3)*2 + i*8
  _Float16* wb = &hp[0][wgrp][((wv << 2) + (r16 >> 2)) * 128 + (g4 << 5) + ((r16 & 3) << 1)];
  // read: plane L, chunk q: halfidx = L*2048 + q*512 + lane*8
  const _Float16* rb = &hp[0][0][lane << 3];

  float* ybase = out + (size_t)(b0 + (g4 << 2)) * HID + (wv << 5) + r16;

  float hf[2][4]; // L0: h0(t);  L1: h1(t-1)

#define RNN_BODY(k)                                                            \
  {                                                                            \
    const int t = t0 + (k);                                                    \
    _Float16* w = wb + (((k) & 1) * 4096);                                     \
    if (isL0) {                                                                \
      const int tp = (t + 3 < SEQ) ? (t + 3) : (SEQ - 1);                      \
      ring[((k) + 3) & 3][0] = xw[xb0 + (size_t)tp * 8192];                    \
      ring[((k) + 3) & 3][1] = xw[xb1 + (size_t)tp * 8192];                    \
      _Pragma("unroll")                                                        \
      for (int n = 0; n < 2; ++n) {                                            \
        f32x4 a0 = seed_cvt(ring[(k)][n]);                                     \
        f32x4 a1 = {0.f, 0.f, 0.f, 0.f};                                       \
        a0 = MFMA16(h0A[0], WA[n][0], a0);                                     \
        a1 = MFMA16(h0A[1], WA[n][1], a1);                                     \
        a0 = MFMA16(h0A[2], WA[n][2], a0);                                     \
        a1 = MFMA16(h0A[3], WA[n][3], a1);                                     \
        _Pragma("unroll")                                                      \
        for (int i = 0; i < 4; ++i) hf[n][i] = fast_tanh(a0[i] + a1[i]);       \
      }                                                                        \
      _Pragma("unroll")                                                        \
      for (int i = 0; i < 4; ++i) {                                            \
        half2v v; v[0] = (_Float16)hf[0][i]; v[1] = (_Float16)hf[1][i];        \
        *(half2v*)(w + i * 8) = v;                                             \
      }                                                                        \
    } else {                                                                   \
      _Pragma("unroll")                                                        \
      for (int n = 0; n < 2; ++n) {                                            \
        f32x4 a0 = {bs[n], bs[n], bs[n], bs[n]};                               \
        f32x4 a1 = {0.f, 0.f, 0.f, 0.f};                                       \
        f32x4 a2 = {0.f, 0.f, 0.f, 0.f};                                       \
        f32x4 a3 = {0.f, 0.f, 0.f, 0.f};                                       \
        a0 = MFMA16(h0A[0], WB[n][0], a0);                                     \
        a1 = MFMA16(h0A[1], WB[n][1], a1);                                     \
        a2 = MFMA16(h0A[2], WB[n][2], a2);                                     \
        a3 = MFMA16(h0A[3], WB[n][3], a3);                                     \
        a0 = MFMA16(h1A[0], WA[n][0], a0);                                     \
        a1 = MFMA16(h1A[1], WA[n][1], a1);                                     \
        a2 = MFMA16(h1A[2], WA[n][2], a2);                                     \
        a3 = MFMA16(h1A[3], WA[n][3], a3);                                     \
        _Pragma("unroll")                                                      \
        for (int i = 0; i < 4; ++i)                                            \
          hf[n][i] = fast_tanh((a0[i] + a1[i]) + (a2[i] + a3[i]));             \
      }                                                                        \
      _Pragma("unroll")                                                        \
      for (int i = 0; i < 4; ++i) {                                            \
        half2v v; v[0] = (_Float16)hf[0][i]; v[1] = (_Float16)hf[1][i];        \
        *(half2v*)(w + i * 8) = v;                                             \
      }                                                                        \
      if (t > 0) {                                                             \
        float* yo = ybase + (size_t)(t - 1) * (BATCH * HID);                   \
        _Pragma("unroll")                                                      \
        for (int n = 0; n < 2; ++n)                                            \
          _Pragma("unroll")                                                    \
          for (int i = 0; i < 4; ++i) yo[i * HID + n * 16] = hf[n][i];         \
      }                                                                        \
    }                                                                          \
    lds_barrier();                                                             \
    {                                                                          \
      const _Float16* r = rb + (((k) & 1) * 4096);                             \
      _Pragma("unroll")                                                        \
      for (int q = 0; q < 4; ++q) h0A[q] = *(const half8*)(r + q * 512);       \
      if (!isL0) {                                                             \
        _Pragma("unroll")                                                      \
        for (int q = 0; q < 4; ++q) h1A[q] = *(const half8*)(r + 2048 + q * 512);\
        if (t == 0) {                                                          \
          _Pragma("unroll")                                                    \
          for (int q = 0; q < 4; ++q) h1A[q] = h8zero();                       \
        }                                                                      \
      }                                                                        \
    }                                                                          \
  }

#pragma unroll 1
  for (int t0 = 0; t0 < SEQ; t0 += 4) {
    RNN_BODY(0)
    RNN_BODY(1)
    RNN_BODY(2)
    RNN_BODY(3)
  }
#undef RNN_BODY

  // ---- epilogue ----
  if (isL0) {
    float* hn0 = out + (size_t)SEQ * BATCH * HID +
                 (size_t)(b0 + (g4 << 2)) * HID + (wv << 5) + r16;
#pragma unroll
    for (int n = 0; n < 2; ++n)
#pragma unroll
      for (int i = 0; i < 4; ++i) hn0[i * HID + n * 16] = hf[n][i];
  } else {
    float h1l[2][4];
#pragma unroll
    for (int n = 0; n < 2; ++n) {
      f32x4 a0 = {bs[n], bs[n], bs[n], bs[n]};
      f32x4 a1 = {0.f, 0.f, 0.f, 0.f};
      f32x4 a2 = {0.f, 0.f, 0.f, 0.f};
      f32x4 a3 = {0.f, 0.f, 0.f, 0.f};
      a0 = MFMA16(h0A[0], WB[n][0], a0);
      a1 = MFMA16(h0A[1], WB[n][1], a1);
      a2 = MFMA16(h0A[2], WB[n][2], a2);
      a3 = MFMA16(h0A[3], WB[n][3], a3);
      a0 = MFMA16(h1A[0], WA[n][0], a0);
      a1 = MFMA16(h1A[1], WA[n][1], a1);
      a2 = MFMA16(h1A[2], WA[n][2], a2);
      a3 = MFMA16(h1A[3], WA[n][3], a3);
#pragma unroll
      for (int i = 0; i < 4; ++i)
        h1l[n][i] = fast_tanh((a0[i] + a1[i]) + (a2[i] + a3[i]));
    }
    float* yo = ybase + (size_t)(SEQ - 1) * (BATCH * HID);
    float* hn1 = out + (size_t)SEQ * BATCH * HID + (size_t)BATCH * HID +
                 (size_t)(b0 + (g4 << 2)) * HID + (wv << 5) + r16;
#pragma unroll
    for (int n = 0; n < 2; ++n)
#pragma unroll
      for (int i = 0; i < 4; ++i) {
        yo[i * HID + n * 16]  = h1l[n][i];
        hn1[i * HID + n * 16] = h1l[n][i];
      }
  }
}

extern "C" void kernel_launch(void* const* d_in, const int* in_sizes, int n_in,
                              void* d_out, int out_size, void* d_ws, size_t ws_size,
                              hipStream_t stream) {
  (void)in_sizes; (void)n_in; (void)out_size;
  const float* x    = (const float*)d_in[0];
  const float* Wih0 = (const float*)d_in[1];
  const float* bih0 = (const float*)d_in[2];
  const float* Whh0 = (const float*)d_in[3];
  const float* bhh0 = (const float*)d_in[4];
  const float* Wih1 = (const float*)d_in[5];
  const float* bih1 = (const float*)d_in[6];
  const float* Whh1 = (const float*)d_in[7];
  const float* bhh1 = (const float*)d_in[8];
  float* out = (float*)d_out;

  const size_t nelem = (size_t)SEQ * BATCH * HID;

  if (ws_size >= nelem * 4) {
    gemm_xw<1><<<512, 256, 0, stream>>>(x, Wih0, bih0, bhh0, d_ws);
    rnn_scan<1><<<16, 512, 0, stream>>>(d_ws, Whh0, Wih1, bih1, Whh1, bhh1, out);
  } else {
    gemm_xw<0><<<512, 256, 0, stream>>>(x, Wih0, bih0, bhh0, d_ws);
    rnn_scan<0><<<16, 512, 0, stream>>>(d_ws, Whh0, Wih1, bih1, Whh1, bhh1, out);
  }
}